// Round 1
// baseline (549.053 us; speedup 1.0000x reference)
//
#include <hip/hip_runtime.h>
#include <cstdint>
#include <cstddef>

namespace {

constexpr int Bb  = 8;
constexpr int Tt  = 1024;
constexpr int Dd  = 768;
constexpr int Hh  = 12;
constexpr int DFF = 3072;
constexpr int BT  = Bb * Tt;

typedef __attribute__((ext_vector_type(8))) short bf16x8;
typedef __attribute__((ext_vector_type(4))) short bf16x4;
typedef __attribute__((ext_vector_type(4))) float f32x4;

__device__ __forceinline__ short f2bf(float f) {
  union { float f; unsigned u; } v; v.f = f;
  unsigned r = v.u + 0x7fffu + ((v.u >> 16) & 1u);   // RNE
  return (short)(r >> 16);
}
__device__ __forceinline__ float gelu_exact(float v) {
  return 0.5f * v * (1.0f + erff(v * 0.70710678118654752f));
}

#define MFMA16(a, b, c) __builtin_amdgcn_mfma_f32_16x16x32_bf16(a, b, c, 0, 0, 0)

// ---------- weight convert + transpose: out[n*K + k] = bf16(in[k*N + n]) ----------
__global__ __launch_bounds__(256) void cvt_t(const float* __restrict__ in,
                                             short* __restrict__ out,
                                             int K, int N) {
  __shared__ float tile[32][33];
  int k0 = blockIdx.x * 32, n0 = blockIdx.y * 32;
  int tx = threadIdx.x & 31, ty = threadIdx.x >> 5;
  #pragma unroll
  for (int r = ty; r < 32; r += 8)
    tile[r][tx] = in[(size_t)(k0 + r) * N + n0 + tx];
  __syncthreads();
  #pragma unroll
  for (int r = ty; r < 32; r += 8)
    out[(size_t)(n0 + r) * K + k0 + tx] = f2bf(tile[tx][r]);
}

// ---------- LayerNorm rows of 768: f32 in -> bf16 out (one wave per row) ----------
__global__ __launch_bounds__(256) void ln_rows(const float* __restrict__ x,
                                               const float* __restrict__ g,
                                               const float* __restrict__ b,
                                               short* __restrict__ out) {
  int lane = threadIdx.x & 63, wid = threadIdx.x >> 6;
  int row = blockIdx.x * 4 + wid;
  const float* xr = x + (size_t)row * Dd;
  float v[12];
  float s = 0.f, ss = 0.f;
  #pragma unroll
  for (int c = 0; c < 3; c++) {
    float4 t = *(const float4*)&xr[c * 256 + lane * 4];
    v[c * 4 + 0] = t.x; v[c * 4 + 1] = t.y; v[c * 4 + 2] = t.z; v[c * 4 + 3] = t.w;
    s  += t.x + t.y + t.z + t.w;
    ss += t.x * t.x + t.y * t.y + t.z * t.z + t.w * t.w;
  }
  #pragma unroll
  for (int off = 1; off < 64; off <<= 1) {
    s += __shfl_xor(s, off); ss += __shfl_xor(ss, off);
  }
  float mu   = s * (1.f / Dd);
  float var  = ss * (1.f / Dd) - mu * mu;   // population var, matches jnp.var
  float rstd = rsqrtf(var + 1e-5f);
  #pragma unroll
  for (int c = 0; c < 3; c++) {
    bf16x4 o;
    #pragma unroll
    for (int j = 0; j < 4; j++) {
      int d = c * 256 + lane * 4 + j;
      o[j] = f2bf((v[c * 4 + j] - mu) * rstd * g[d] + b[d]);
    }
    *(bf16x4*)&out[(size_t)row * Dd + c * 256 + lane * 4] = o;
  }
}

// ---------- GEMM: C[M,N] = A[M,K](bf16) * Bt[N,K]^T(bf16) + bias, epilogue variants ----------
// EPI 0: out bf16 = acc+bias          (QKV)
// EPI 1: out f32  = acc+bias+add      (out-proj + residual)
// EPI 2: out bf16 = gelu(acc+bias)    (fc1)
// EPI 3: out f32  = acc+bias+add      (fc2 + residual)
template <int EPI, int N>
__global__ __launch_bounds__(256) void gemm_bt(const short* __restrict__ A,
                                               const short* __restrict__ Bt,
                                               const float* __restrict__ bias,
                                               const float* __restrict__ add,
                                               void* __restrict__ outp,
                                               int K) {
  __shared__ short As[128][40];   // +8 pad: 80B stride -> 2-way (free) on frag reads
  __shared__ short Bs[128][40];
  int m0 = blockIdx.x * 128, n0 = blockIdx.y * 128;
  int tid = threadIdx.x;
  int lane = tid & 63, wid = tid >> 6;
  int wm = wid >> 1, wn = wid & 1;
  int l15 = lane & 15, lg = lane >> 4;
  f32x4 acc[4][4] = {};
  int sr = tid >> 2, sc = (tid & 3) * 8;
  for (int k0 = 0; k0 < K; k0 += 32) {
    *(bf16x8*)&As[sr     ][sc] = *(const bf16x8*)&A [(size_t)(m0 + sr     ) * K + k0 + sc];
    *(bf16x8*)&As[sr + 64][sc] = *(const bf16x8*)&A [(size_t)(m0 + sr + 64) * K + k0 + sc];
    *(bf16x8*)&Bs[sr     ][sc] = *(const bf16x8*)&Bt[(size_t)(n0 + sr     ) * K + k0 + sc];
    *(bf16x8*)&Bs[sr + 64][sc] = *(const bf16x8*)&Bt[(size_t)(n0 + sr + 64) * K + k0 + sc];
    __syncthreads();
    bf16x8 af[4], bfr[4];
    #pragma unroll
    for (int i = 0; i < 4; i++) af[i]  = *(bf16x8*)&As[wm * 64 + i * 16 + l15][lg * 8];
    #pragma unroll
    for (int j = 0; j < 4; j++) bfr[j] = *(bf16x8*)&Bs[wn * 64 + j * 16 + l15][lg * 8];
    #pragma unroll
    for (int i = 0; i < 4; i++)
      #pragma unroll
      for (int j = 0; j < 4; j++)
        acc[i][j] = MFMA16(af[i], bfr[j], acc[i][j]);
    __syncthreads();
  }
  #pragma unroll
  for (int i = 0; i < 4; i++) {
    #pragma unroll
    for (int j = 0; j < 4; j++) {
      #pragma unroll
      for (int r = 0; r < 4; r++) {
        int m = m0 + wm * 64 + i * 16 + lg * 4 + r;   // D row = (lane>>4)*4+reg
        int n = n0 + wn * 64 + j * 16 + l15;          // D col = lane&15
        float vv = acc[i][j][r] + bias[n];
        size_t idx = (size_t)m * N + n;
        if (EPI == 0)      ((short*)outp)[idx] = f2bf(vv);
        else if (EPI == 1) ((float*)outp)[idx] = vv + add[idx];
        else if (EPI == 2) ((short*)outp)[idx] = f2bf(gelu_exact(vv));
        else               ((float*)outp)[idx] = vv + add[idx];
      }
    }
  }
}

// ---------- fused causal attention ----------
// grid (T/64, B*H), 256 thr (4 waves). Wave w owns 16 q-rows; two-pass online softmax.
// Writes attn_weights f32 (mandatory 402 MB) + ctx bf16 [BT, 768].
__global__ __launch_bounds__(256) void attn_fused(const short* __restrict__ qkv,
                                                  float* __restrict__ attw,
                                                  short* __restrict__ ctx) {
  __shared__ short Vt[64][72];       // V^T tile, padded stride
  __shared__ short Pl[4][16][72];    // per-wave P staging (C-layout -> A-layout)
  int q0 = blockIdx.x * 64;
  int bh = blockIdx.y;
  int b = bh / Hh, h = bh % Hh;
  int tid = threadIdx.x, lane = tid & 63, wid = tid >> 6;
  int l15 = lane & 15, lg = lane >> 4;
  const short* base = qkv + (size_t)b * Tt * 2304;

  // Q fragments (A layout: row=lane&15, k=(lane>>4)*8 contiguous), direct from global
  bf16x8 qa[2];
  {
    const short* qp = base + (size_t)(q0 + wid * 16 + l15) * 2304 + h * 64 + lg * 8;
    qa[0] = *(const bf16x8*)qp;
    qa[1] = *(const bf16x8*)(qp + 32);
  }
  float m[4], l[4];
  #pragma unroll
  for (int r = 0; r < 4; r++) { m[r] = -3e38f; l[r] = 0.f; }
  const int kt_hi  = (q0 + wid * 16 + 15) >> 6;  // last tile with any valid col, this wave
  const int kt_blk = (q0 + 63) >> 6;             // last tile with any valid col, whole block

  // ---- pass 1: online max/sumexp, scores discarded ----
  for (int kt = 0; kt <= kt_hi; ++kt) {
    f32x4 acc[4] = {};
    #pragma unroll
    for (int nf = 0; nf < 4; ++nf) {
      const short* kp = base + (size_t)(kt * 64 + nf * 16 + l15) * 2304 + 768 + h * 64 + lg * 8;
      bf16x8 k0 = *(const bf16x8*)kp;
      bf16x8 k1 = *(const bf16x8*)(kp + 32);
      acc[nf] = MFMA16(qa[0], k0, acc[nf]);
      acc[nf] = MFMA16(qa[1], k1, acc[nf]);
    }
    #pragma unroll
    for (int r = 0; r < 4; r++) {
      int qg = q0 + wid * 16 + lg * 4 + r;
      float sv[4]; float tmax = -3e38f;
      #pragma unroll
      for (int nf = 0; nf < 4; nf++) {
        int kg = kt * 64 + nf * 16 + l15;
        float sc = acc[nf][r] * 0.125f;
        if (kg > qg) sc = -3e38f;
        sv[nf] = sc;
        tmax = fmaxf(tmax, sc);
      }
      #pragma unroll
      for (int off = 1; off < 16; off <<= 1) tmax = fmaxf(tmax, __shfl_xor(tmax, off));
      float mn = fmaxf(m[r], tmax);
      float ps = 0.f;
      #pragma unroll
      for (int nf = 0; nf < 4; nf++) ps += __expf(sv[nf] - mn);
      #pragma unroll
      for (int off = 1; off < 16; off <<= 1) ps += __shfl_xor(ps, off);
      l[r] = l[r] * __expf(m[r] - mn) + ps;
      m[r] = mn;
    }
  }
  float rl[4];
  #pragma unroll
  for (int r = 0; r < 4; r++) rl[r] = 1.f / l[r];

  // ---- pass 2: recompute scores, write attn_weights, accumulate PV ----
  f32x4 oacc[4] = {};
  for (int kt = 0; kt < Tt / 64; ++kt) {
    if (kt <= kt_blk) {                     // uniform branch across block
      __syncthreads();
      int t = tid & 63, dv = (tid >> 6) * 16;
      const short* vp = base + (size_t)(kt * 64 + t) * 2304 + 1536 + h * 64 + dv;
      bf16x8 v0 = *(const bf16x8*)vp;
      bf16x8 v1 = *(const bf16x8*)(vp + 8);
      #pragma unroll
      for (int j = 0; j < 8; j++) Vt[dv + j][t] = v0[j];
      #pragma unroll
      for (int j = 0; j < 8; j++) Vt[dv + 8 + j][t] = v1[j];
      __syncthreads();
    }
    if (kt <= kt_hi) {                      // wave-divergent OK: no barrier inside
      f32x4 acc[4] = {};
      #pragma unroll
      for (int nf = 0; nf < 4; nf++) {
        const short* kp = base + (size_t)(kt * 64 + nf * 16 + l15) * 2304 + 768 + h * 64 + lg * 8;
        bf16x8 k0 = *(const bf16x8*)kp;
        bf16x8 k1 = *(const bf16x8*)(kp + 32);
        acc[nf] = MFMA16(qa[0], k0, acc[nf]);
        acc[nf] = MFMA16(qa[1], k1, acc[nf]);
      }
      #pragma unroll
      for (int nf = 0; nf < 4; nf++) {
        #pragma unroll
        for (int r = 0; r < 4; r++) {
          int qg = q0 + wid * 16 + lg * 4 + r;
          int kg = kt * 64 + nf * 16 + l15;
          float sc = acc[nf][r] * 0.125f;
          float p = (kg <= qg) ? __expf(sc - m[r]) * rl[r] : 0.f;
          attw[((size_t)bh * Tt + qg) * Tt + kg] = p;
          Pl[wid][lg * 4 + r][nf * 16 + l15] = f2bf(p);
        }
      }
      asm volatile("s_waitcnt lgkmcnt(0)" ::: "memory");  // cross-lane LDS RAW within wave
      bf16x8 pa0 = *(bf16x8*)&Pl[wid][l15][lg * 8];
      bf16x8 pa1 = *(bf16x8*)&Pl[wid][l15][lg * 8 + 32];
      #pragma unroll
      for (int nf = 0; nf < 4; nf++) {
        bf16x8 vb0 = *(bf16x8*)&Vt[nf * 16 + l15][lg * 8];
        bf16x8 vb1 = *(bf16x8*)&Vt[nf * 16 + l15][lg * 8 + 32];
        oacc[nf] = MFMA16(pa0, vb0, oacc[nf]);
        oacc[nf] = MFMA16(pa1, vb1, oacc[nf]);
      }
    } else {
      #pragma unroll
      for (int nf = 0; nf < 4; nf++) {
        #pragma unroll
        for (int r = 0; r < 4; r++) {
          int qg = q0 + wid * 16 + lg * 4 + r;
          int kg = kt * 64 + nf * 16 + l15;
          attw[((size_t)bh * Tt + qg) * Tt + kg] = 0.f;
        }
      }
    }
  }
  #pragma unroll
  for (int nf = 0; nf < 4; nf++) {
    #pragma unroll
    for (int r = 0; r < 4; r++) {
      int t = q0 + wid * 16 + lg * 4 + r;
      ctx[((size_t)b * Tt + t) * Dd + h * 64 + nf * 16 + l15] = f2bf(oacc[nf][r]);
    }
  }
}

}  // namespace

extern "C" void kernel_launch(void* const* d_in, const int* in_sizes, int n_in,
                              void* d_out, int out_size, void* d_ws, size_t ws_size,
                              hipStream_t stream) {
  const float* x     = (const float*)d_in[0];
  const float* ln1g  = (const float*)d_in[1];
  const float* ln1b  = (const float*)d_in[2];
  const float* w_qkv = (const float*)d_in[3];
  const float* b_qkv = (const float*)d_in[4];
  const float* w_out = (const float*)d_in[5];
  const float* b_out = (const float*)d_in[6];
  const float* ln2g  = (const float*)d_in[7];
  const float* ln2b  = (const float*)d_in[8];
  const float* w_fc1 = (const float*)d_in[9];
  const float* b_fc1 = (const float*)d_in[10];
  const float* w_fc2 = (const float*)d_in[11];
  const float* b_fc2 = (const float*)d_in[12];

  // workspace layout (~102.3 MB, regions reused once dead)
  char* ws = (char*)d_ws;
  size_t o = 0;
  short* wqkvT = (short*)(ws + o); o += (size_t)2304 * 768 * 2;   // 3.54 MB
  short* woutT = (short*)(ws + o); o += (size_t)768 * 768 * 2;    // 1.18 MB
  short* wfc1T = (short*)(ws + o); o += (size_t)3072 * 768 * 2;   // 4.72 MB
  short* wfc2T = (short*)(ws + o); o += (size_t)768 * 3072 * 2;   // 4.72 MB
  short* h     = (short*)(ws + o); o += (size_t)BT * Dd * 2;      // 12.58 MB
  short* qkv   = (short*)(ws + o); o += (size_t)BT * 2304 * 2;    // 37.75 MB
  float* y1    = (float*)(ws + o); o += (size_t)BT * Dd * 4;      // 25.17 MB
  short* h2    = (short*)(ws + o); o += (size_t)BT * Dd * 2;      // 12.58 MB
  short* ctx  = h;     // reuse: h dead after QKV GEMM
  short* gbuf = h;     // reuse: h+qkv regions (exactly BT*DFF*2 bytes) for GELU output

  float* out_x = (float*)d_out;
  float* attw  = out_x + (size_t)BT * Dd;

  // 1. weights -> bf16 transposed
  cvt_t<<<dim3(768 / 32, 2304 / 32), 256, 0, stream>>>(w_qkv, wqkvT, 768, 2304);
  cvt_t<<<dim3(768 / 32, 768 / 32),  256, 0, stream>>>(w_out, woutT, 768, 768);
  cvt_t<<<dim3(768 / 32, 3072 / 32), 256, 0, stream>>>(w_fc1, wfc1T, 768, 3072);
  cvt_t<<<dim3(3072 / 32, 768 / 32), 256, 0, stream>>>(w_fc2, wfc2T, 3072, 768);

  // 2. LN1
  ln_rows<<<BT / 4, 256, 0, stream>>>(x, ln1g, ln1b, h);
  // 3. QKV
  gemm_bt<0, 2304><<<dim3(BT / 128, 2304 / 128), 256, 0, stream>>>(h, wqkvT, b_qkv, nullptr, qkv, 768);
  // 4. attention (writes attn_weights to d_out + ctx)
  attn_fused<<<dim3(Tt / 64, Bb * Hh), 256, 0, stream>>>(qkv, attw, ctx);
  // 5. out-proj + residual -> y1 (f32)
  gemm_bt<1, 768><<<dim3(BT / 128, 768 / 128), 256, 0, stream>>>(ctx, woutT, b_out, x, y1, 768);
  // 6. LN2
  ln_rows<<<BT / 4, 256, 0, stream>>>(y1, ln2g, ln2b, h2);
  // 7. fc1 + GELU
  gemm_bt<2, 3072><<<dim3(BT / 128, 3072 / 128), 256, 0, stream>>>(h2, wfc1T, b_fc1, nullptr, gbuf, 768);
  // 8. fc2 + residual -> final x (d_out)
  gemm_bt<3, 768><<<dim3(BT / 128, 768 / 128), 256, 0, stream>>>(gbuf, wfc2T, b_fc2, y1, out_x, 3072);
}

// Round 2
// 484.408 us; speedup vs baseline: 1.1335x; 1.1335x over previous
//
#include <hip/hip_runtime.h>
#include <cstdint>
#include <cstddef>

namespace {

constexpr int Bb  = 8;
constexpr int Tt  = 1024;
constexpr int Dd  = 768;
constexpr int Hh  = 12;
constexpr int DFF = 3072;
constexpr int BT  = Bb * Tt;

typedef __attribute__((ext_vector_type(8))) short bf16x8;
typedef __attribute__((ext_vector_type(4))) short bf16x4;
typedef __attribute__((ext_vector_type(4))) float f32x4;

__device__ __forceinline__ short f2bf(float f) {
  union { float f; unsigned u; } v; v.f = f;
  unsigned r = v.u + 0x7fffu + ((v.u >> 16) & 1u);   // RNE
  return (short)(r >> 16);
}
__device__ __forceinline__ float gelu_exact(float v) {
  return 0.5f * v * (1.0f + erff(v * 0.70710678118654752f));
}

#define MFMA16(a, b, c) __builtin_amdgcn_mfma_f32_16x16x32_bf16(a, b, c, 0, 0, 0)

// ---------- weight convert + transpose: out[n*K + k] = bf16(in[k*N + n]) ----------
__global__ __launch_bounds__(256) void cvt_t(const float* __restrict__ in,
                                             short* __restrict__ out,
                                             int K, int N) {
  __shared__ float tile[32][33];
  int k0 = blockIdx.x * 32, n0 = blockIdx.y * 32;
  int tx = threadIdx.x & 31, ty = threadIdx.x >> 5;
  #pragma unroll
  for (int r = ty; r < 32; r += 8)
    tile[r][tx] = in[(size_t)(k0 + r) * N + n0 + tx];
  __syncthreads();
  #pragma unroll
  for (int r = ty; r < 32; r += 8)
    out[(size_t)(n0 + r) * K + k0 + tx] = f2bf(tile[tx][r]);
}

// ---------- LayerNorm rows of 768: f32 in -> bf16 out (one wave per row) ----------
__global__ __launch_bounds__(256) void ln_rows(const float* __restrict__ x,
                                               const float* __restrict__ g,
                                               const float* __restrict__ b,
                                               short* __restrict__ out) {
  int lane = threadIdx.x & 63, wid = threadIdx.x >> 6;
  int row = blockIdx.x * 4 + wid;
  const float* xr = x + (size_t)row * Dd;
  float v[12];
  float s = 0.f, ss = 0.f;
  #pragma unroll
  for (int c = 0; c < 3; c++) {
    float4 t = *(const float4*)&xr[c * 256 + lane * 4];
    v[c * 4 + 0] = t.x; v[c * 4 + 1] = t.y; v[c * 4 + 2] = t.z; v[c * 4 + 3] = t.w;
    s  += t.x + t.y + t.z + t.w;
    ss += t.x * t.x + t.y * t.y + t.z * t.z + t.w * t.w;
  }
  #pragma unroll
  for (int off = 1; off < 64; off <<= 1) {
    s += __shfl_xor(s, off); ss += __shfl_xor(ss, off);
  }
  float mu   = s * (1.f / Dd);
  float var  = ss * (1.f / Dd) - mu * mu;   // population var, matches jnp.var
  float rstd = rsqrtf(var + 1e-5f);
  #pragma unroll
  for (int c = 0; c < 3; c++) {
    bf16x4 o;
    #pragma unroll
    for (int j = 0; j < 4; j++) {
      int d = c * 256 + lane * 4 + j;
      o[j] = f2bf((v[c * 4 + j] - mu) * rstd * g[d] + b[d]);
    }
    *(bf16x4*)&out[(size_t)row * Dd + c * 256 + lane * 4] = o;
  }
}

// ---------- GEMM: C[M,N] = A[M,K](bf16) * Bt[N,K]^T(bf16) + bias, epilogue variants ----------
template <int EPI, int N>
__global__ __launch_bounds__(256) void gemm_bt(const short* __restrict__ A,
                                               const short* __restrict__ Bt,
                                               const float* __restrict__ bias,
                                               const float* __restrict__ add,
                                               void* __restrict__ outp,
                                               int K) {
  __shared__ short As[128][40];   // +8 pad: 80B stride -> 2-way (free) on frag reads
  __shared__ short Bs[128][40];
  int m0 = blockIdx.x * 128, n0 = blockIdx.y * 128;
  int tid = threadIdx.x;
  int lane = tid & 63, wid = tid >> 6;
  int wm = wid >> 1, wn = wid & 1;
  int l15 = lane & 15, lg = lane >> 4;
  f32x4 acc[4][4] = {};
  int sr = tid >> 2, sc = (tid & 3) * 8;
  for (int k0 = 0; k0 < K; k0 += 32) {
    *(bf16x8*)&As[sr     ][sc] = *(const bf16x8*)&A [(size_t)(m0 + sr     ) * K + k0 + sc];
    *(bf16x8*)&As[sr + 64][sc] = *(const bf16x8*)&A [(size_t)(m0 + sr + 64) * K + k0 + sc];
    *(bf16x8*)&Bs[sr     ][sc] = *(const bf16x8*)&Bt[(size_t)(n0 + sr     ) * K + k0 + sc];
    *(bf16x8*)&Bs[sr + 64][sc] = *(const bf16x8*)&Bt[(size_t)(n0 + sr + 64) * K + k0 + sc];
    __syncthreads();
    bf16x8 af[4], bfr[4];
    #pragma unroll
    for (int i = 0; i < 4; i++) af[i]  = *(bf16x8*)&As[wm * 64 + i * 16 + l15][lg * 8];
    #pragma unroll
    for (int j = 0; j < 4; j++) bfr[j] = *(bf16x8*)&Bs[wn * 64 + j * 16 + l15][lg * 8];
    #pragma unroll
    for (int i = 0; i < 4; i++)
      #pragma unroll
      for (int j = 0; j < 4; j++)
        acc[i][j] = MFMA16(af[i], bfr[j], acc[i][j]);
    __syncthreads();
  }
  #pragma unroll
  for (int i = 0; i < 4; i++) {
    #pragma unroll
    for (int j = 0; j < 4; j++) {
      #pragma unroll
      for (int r = 0; r < 4; r++) {
        int m = m0 + wm * 64 + i * 16 + lg * 4 + r;
        int n = n0 + wn * 64 + j * 16 + l15;
        float vv = acc[i][j][r] + bias[n];
        size_t idx = (size_t)m * N + n;
        if (EPI == 0)      ((short*)outp)[idx] = f2bf(vv);
        else if (EPI == 1) ((float*)outp)[idx] = vv + add[idx];
        else if (EPI == 2) ((short*)outp)[idx] = f2bf(gelu_exact(vv));
        else               ((float*)outp)[idx] = vv + add[idx];
      }
    }
  }
}

// ---------- fused causal attention ----------
// grid (16, 96) remapped: all 16 q-tiles of one (b,h) on one XCD (K/V stay L2-local),
// heavy (high-tile) blocks dispatched first (LPT). 4 waves, wave w owns q-rows
// [q0+16w, q0+16w+16). Two-pass online softmax; attw written via f32 LDS staging
// with float4 coalesced stores.
__global__ __launch_bounds__(256) void attn_fused(const short* __restrict__ qkv,
                                                  float* __restrict__ attw,
                                                  short* __restrict__ ctx) {
  __shared__ short Vt[64][72];       // V^T tile (9.2 KB)
  __shared__ float Pf[4][16][68];    // per-wave P f32 staging (17.4 KB); 68 = 4 mod 32 banks, 16B-aligned rows
  int flat = blockIdx.y * 16 + blockIdx.x;
  int xcd = flat & 7, rr0 = flat >> 3;
  int bh   = xcd * 12 + (rr0 >> 4);          // 12 heads-worth per XCD
  int tile = 15 - (rr0 & 15);                // heavy first (LPT)
  int q0 = tile * 64;
  int b = bh / Hh, h = bh % Hh;
  int tid = threadIdx.x, lane = tid & 63, wid = tid >> 6;
  int l15 = lane & 15, lg = lane >> 4;
  const short* base = qkv + (size_t)b * Tt * 2304;

  // Q fragments (A layout: row=lane&15, k=(lane>>4)*8 contiguous)
  bf16x8 qa[2];
  {
    const short* qp = base + (size_t)(q0 + wid * 16 + l15) * 2304 + h * 64 + lg * 8;
    qa[0] = *(const bf16x8*)qp;
    qa[1] = *(const bf16x8*)(qp + 32);
  }
  float m[4], l[4];
  #pragma unroll
  for (int r = 0; r < 4; r++) { m[r] = -3e38f; l[r] = 0.f; }

  // ---- pass 1: online max/sumexp, scores discarded ----
  for (int kt = 0; kt <= tile; ++kt) {
    f32x4 acc[4] = {};
    #pragma unroll
    for (int nf = 0; nf < 4; ++nf) {
      const short* kp = base + (size_t)(kt * 64 + nf * 16 + l15) * 2304 + 768 + h * 64 + lg * 8;
      bf16x8 k0 = *(const bf16x8*)kp;
      bf16x8 k1 = *(const bf16x8*)(kp + 32);
      acc[nf] = MFMA16(qa[0], k0, acc[nf]);
      acc[nf] = MFMA16(qa[1], k1, acc[nf]);
    }
    #pragma unroll
    for (int r = 0; r < 4; r++) {
      int qg = q0 + wid * 16 + lg * 4 + r;
      float sv[4]; float tmax = -3e38f;
      #pragma unroll
      for (int nf = 0; nf < 4; nf++) {
        int kg = kt * 64 + nf * 16 + l15;
        float sc = acc[nf][r] * 0.125f;
        if (kg > qg) sc = -3e38f;
        sv[nf] = sc;
        tmax = fmaxf(tmax, sc);
      }
      #pragma unroll
      for (int off = 1; off < 16; off <<= 1) tmax = fmaxf(tmax, __shfl_xor(tmax, off));
      float mn = fmaxf(m[r], tmax);
      float ps = 0.f;
      #pragma unroll
      for (int nf = 0; nf < 4; nf++) ps += __expf(sv[nf] - mn);
      #pragma unroll
      for (int off = 1; off < 16; off <<= 1) ps += __shfl_xor(ps, off);
      l[r] = l[r] * __expf(m[r] - mn) + ps;
      m[r] = mn;
    }
  }
  float rl[4];
  #pragma unroll
  for (int r = 0; r < 4; r++) rl[r] = 1.f / l[r];

  // ---- pass 2: recompute scores, write attw (coalesced), accumulate PV ----
  f32x4 oacc[4] = {};
  for (int kt = 0; kt <= tile; ++kt) {
    __syncthreads();                         // protect previous Vt reads
    {
      int t = tid & 63, dv = (tid >> 6) * 16;
      const short* vp = base + (size_t)(kt * 64 + t) * 2304 + 1536 + h * 64 + dv;
      bf16x8 v0 = *(const bf16x8*)vp;
      bf16x8 v1 = *(const bf16x8*)(vp + 8);
      #pragma unroll
      for (int j = 0; j < 8; j++) Vt[dv + j][t] = v0[j];
      #pragma unroll
      for (int j = 0; j < 8; j++) Vt[dv + 8 + j][t] = v1[j];
    }
    __syncthreads();

    f32x4 acc[4] = {};
    #pragma unroll
    for (int nf = 0; nf < 4; nf++) {
      const short* kp = base + (size_t)(kt * 64 + nf * 16 + l15) * 2304 + 768 + h * 64 + lg * 8;
      bf16x8 k0 = *(const bf16x8*)kp;
      bf16x8 k1 = *(const bf16x8*)(kp + 32);
      acc[nf] = MFMA16(qa[0], k0, acc[nf]);
      acc[nf] = MFMA16(qa[1], k1, acc[nf]);
    }
    #pragma unroll
    for (int nf = 0; nf < 4; nf++) {
      #pragma unroll
      for (int r = 0; r < 4; r++) {
        int qg = q0 + wid * 16 + lg * 4 + r;
        int kg = kt * 64 + nf * 16 + l15;
        float sc = acc[nf][r] * 0.125f;
        float p = (kg <= qg) ? __expf(sc - m[r]) * rl[r] : 0.f;
        Pf[wid][lg * 4 + r][nf * 16 + l15] = p;
      }
    }
    asm volatile("s_waitcnt lgkmcnt(0)" ::: "memory");
    __builtin_amdgcn_sched_barrier(0);
    // coalesced attw write: float4, 256B segments per row
    #pragma unroll
    for (int it = 0; it < 4; ++it) {
      int pr = it * 4 + lg;
      f32x4 pv = *(f32x4*)&Pf[wid][pr][l15 * 4];
      *(f32x4*)&attw[((size_t)bh * Tt + q0 + wid * 16 + pr) * Tt + kt * 64 + l15 * 4] = pv;
    }
    // A-fragments from Pf (convert f32 -> bf16 in-register)
    f32x4 pf0 = *(f32x4*)&Pf[wid][l15][lg * 8];
    f32x4 pf1 = *(f32x4*)&Pf[wid][l15][lg * 8 + 4];
    f32x4 pf2 = *(f32x4*)&Pf[wid][l15][lg * 8 + 32];
    f32x4 pf3 = *(f32x4*)&Pf[wid][l15][lg * 8 + 36];
    bf16x8 pa0, pa1;
    #pragma unroll
    for (int j = 0; j < 4; j++) {
      pa0[j] = f2bf(pf0[j]); pa0[4 + j] = f2bf(pf1[j]);
      pa1[j] = f2bf(pf2[j]); pa1[4 + j] = f2bf(pf3[j]);
    }
    #pragma unroll
    for (int nf = 0; nf < 4; nf++) {
      bf16x8 vb0 = *(bf16x8*)&Vt[nf * 16 + l15][lg * 8];
      bf16x8 vb1 = *(bf16x8*)&Vt[nf * 16 + l15][lg * 8 + 32];
      oacc[nf] = MFMA16(pa0, vb0, oacc[nf]);
      oacc[nf] = MFMA16(pa1, vb1, oacc[nf]);
    }
  }
  // strictly-upper zero tiles: float4 zero stores, no barriers
  for (int kt = tile + 1; kt < 16; ++kt) {
    #pragma unroll
    for (int it = 0; it < 4; ++it) {
      int pr = it * 4 + lg;
      f32x4 z = {0.f, 0.f, 0.f, 0.f};
      *(f32x4*)&attw[((size_t)bh * Tt + q0 + wid * 16 + pr) * Tt + kt * 64 + l15 * 4] = z;
    }
  }
  #pragma unroll
  for (int nf = 0; nf < 4; nf++) {
    #pragma unroll
    for (int r = 0; r < 4; r++) {
      int t = q0 + wid * 16 + lg * 4 + r;
      ctx[((size_t)b * Tt + t) * Dd + h * 64 + nf * 16 + l15] = f2bf(oacc[nf][r]);
    }
  }
}

}  // namespace

extern "C" void kernel_launch(void* const* d_in, const int* in_sizes, int n_in,
                              void* d_out, int out_size, void* d_ws, size_t ws_size,
                              hipStream_t stream) {
  const float* x     = (const float*)d_in[0];
  const float* ln1g  = (const float*)d_in[1];
  const float* ln1b  = (const float*)d_in[2];
  const float* w_qkv = (const float*)d_in[3];
  const float* b_qkv = (const float*)d_in[4];
  const float* w_out = (const float*)d_in[5];
  const float* b_out = (const float*)d_in[6];
  const float* ln2g  = (const float*)d_in[7];
  const float* ln2b  = (const float*)d_in[8];
  const float* w_fc1 = (const float*)d_in[9];
  const float* b_fc1 = (const float*)d_in[10];
  const float* w_fc2 = (const float*)d_in[11];
  const float* b_fc2 = (const float*)d_in[12];

  char* ws = (char*)d_ws;
  size_t o = 0;
  short* wqkvT = (short*)(ws + o); o += (size_t)2304 * 768 * 2;
  short* woutT = (short*)(ws + o); o += (size_t)768 * 768 * 2;
  short* wfc1T = (short*)(ws + o); o += (size_t)3072 * 768 * 2;
  short* wfc2T = (short*)(ws + o); o += (size_t)768 * 3072 * 2;
  short* h     = (short*)(ws + o); o += (size_t)BT * Dd * 2;
  short* qkv   = (short*)(ws + o); o += (size_t)BT * 2304 * 2;
  float* y1    = (float*)(ws + o); o += (size_t)BT * Dd * 4;
  short* h2    = (short*)(ws + o); o += (size_t)BT * Dd * 2;
  short* ctx  = h;     // reuse: h dead after QKV GEMM
  short* gbuf = h;     // reuse: h+qkv regions for GELU output (BT*DFF*2 bytes)

  float* out_x = (float*)d_out;
  float* attw  = out_x + (size_t)BT * Dd;

  cvt_t<<<dim3(768 / 32, 2304 / 32), 256, 0, stream>>>(w_qkv, wqkvT, 768, 2304);
  cvt_t<<<dim3(768 / 32, 768 / 32),  256, 0, stream>>>(w_out, woutT, 768, 768);
  cvt_t<<<dim3(768 / 32, 3072 / 32), 256, 0, stream>>>(w_fc1, wfc1T, 768, 3072);
  cvt_t<<<dim3(3072 / 32, 768 / 32), 256, 0, stream>>>(w_fc2, wfc2T, 3072, 768);

  ln_rows<<<BT / 4, 256, 0, stream>>>(x, ln1g, ln1b, h);
  gemm_bt<0, 2304><<<dim3(BT / 128, 2304 / 128), 256, 0, stream>>>(h, wqkvT, b_qkv, nullptr, qkv, 768);
  attn_fused<<<dim3(16, 96), 256, 0, stream>>>(qkv, attw, ctx);
  gemm_bt<1, 768><<<dim3(BT / 128, 768 / 128), 256, 0, stream>>>(ctx, woutT, b_out, x, y1, 768);
  ln_rows<<<BT / 4, 256, 0, stream>>>(y1, ln2g, ln2b, h2);
  gemm_bt<2, 3072><<<dim3(BT / 128, 3072 / 128), 256, 0, stream>>>(h2, wfc1T, b_fc1, nullptr, gbuf, 768);
  gemm_bt<3, 768><<<dim3(BT / 128, 768 / 128), 256, 0, stream>>>(gbuf, wfc2T, b_fc2, y1, out_x, 3072);
}